// Round 7
// baseline (156.619 us; speedup 1.0000x reference)
//
#include <hip/hip_runtime.h>
#include <hip/hip_bf16.h>
#include <stdint.h>
#include <stddef.h>

#define AS1 __attribute__((address_space(1)))
#define AS3 __attribute__((address_space(3)))

typedef __attribute__((ext_vector_type(8))) __bf16 bf16x8;
typedef __attribute__((ext_vector_type(4))) float f32x4;
typedef __attribute__((ext_vector_type(4))) unsigned int u32x4;

static __device__ __forceinline__ unsigned short f2bf(float f) {
    unsigned u = __builtin_bit_cast(unsigned, f);
    u += 0x7FFFu + ((u >> 16) & 1u);
    return (unsigned short)(u >> 16);
}

// ---------------- kernel 1: t2 = depthwise (3,1) conv, store NHWC bf16, H padded by 9 ----
__global__ void k_t2prep(const float* __restrict__ x, const float* __restrict__ w2,
                         unsigned short* __restrict__ t2p) {
    const int b = blockIdx.x;
    const int n = b / 74, hp = b % 74;
    const int t = threadIdx.x;
    unsigned short* orow = t2p + (size_t)(n * 74 + hp) * (56 * 256);
    const int h = hp - 9;
    if (h < 0 || h >= 56) {
        u32x4 z = {0u, 0u, 0u, 0u};
        #pragma unroll
        for (int i = 0; i < 7; ++i)
            *(u32x4*)(orow + (size_t)(i * 256 + t) * 8) = z;
        return;
    }
    __shared__ float xs[3][64][57];
    __shared__ float w2s[64][3];
    for (int cc = 0; cc < 256; cc += 64) {
        if (cc) __syncthreads();
        if (t < 192) w2s[t / 3][t % 3] = w2[(cc + t / 3) * 3 + (t % 3)];
        for (int idx = t; idx < 2688; idx += 256) {
            int r = idx / 896, rem = idx % 896;
            int ci = rem / 14, q = rem % 14;
            int hy = h - 1 + r;
            f32x4 v = {0.f, 0.f, 0.f, 0.f};
            if (hy >= 0 && hy < 56)
                v = *(const f32x4*)(x + (size_t)((n * 256 + cc + ci) * 56 + hy) * 56 + q * 4);
            xs[r][ci][q * 4 + 0] = v[0];
            xs[r][ci][q * 4 + 1] = v[1];
            xs[r][ci][q * 4 + 2] = v[2];
            xs[r][ci][q * 4 + 3] = v[3];
        }
        __syncthreads();
        const int c = t & 63;
        const float a0 = w2s[c][0], a1 = w2s[c][1], a2 = w2s[c][2];
        #pragma unroll
        for (int i = 0; i < 14; ++i) {
            int w = i * 4 + (t >> 6);
            float v = a0 * xs[0][c][w] + a1 * xs[1][c][w] + a2 * xs[2][c][w];
            orow[w * 256 + cc + c] = f2bf(v);
        }
    }
}

// ---------------- kernel 1b: w4 reorder + bf16 convert: w4b[o][k*256+c] = w4[o][c*7+k] ----
__global__ void k_w4conv(const float* __restrict__ w4, unsigned short* __restrict__ w4b) {
    int tid = blockIdx.x * 256 + threadIdx.x;
    int o = tid / 1792, j = tid % 1792;
    int k = j >> 8, c = j & 255;
    w4b[tid] = f2bf(w4[o * 1792 + c * 7 + k]);
}

// ---------------- kernel 2: 8-phase 256x256 GEMM (round-3 proven) + t1-gate epilogue ----
// A = w4b [256 o x 1792 K], B[K][pix] from t2p NHWC. BK=64, 28 K-tiles, dbuf LDS 128KB.
// 8 waves: wr = pixel half (2), wc = o quarter (4); per-wave C = 128 pix x 64 o.
// Epilogue: out = acc * t1 (t1 pre-written into d_out by k_t1).
__global__ __launch_bounds__(512, 2) void k_gemm8(const unsigned short* __restrict__ w4b,
                                                  const unsigned short* __restrict__ t2p,
                                                  float* __restrict__ out) {
    extern __shared__ char lds[];                 // 131072 B: [buf][A 32K | B 32K]
    const int pix0 = blockIdx.x * 256;
    const int t = threadIdx.x;
    const int l = t & 63, wv = t >> 6;
    const int wr = wv >> 2, wc = wv & 3;

    // ---- staging bases (bytes), pre-swizzled source (rule 21 involution) ----
    const int srow = t >> 3;                      // 0..63 within a 64-row load
    const int segp = (t & 7) ^ (srow & 7);
    unsigned abase[4], bbase[4];
    #pragma unroll
    for (int j = 0; j < 4; ++j) {
        int arow = j * 64 + srow;                 // o row
        abase[j] = (unsigned)arow * 3584u + (unsigned)segp * 16u;
        int P = pix0 + j * 64 + srow;             // pixel row (always < 50176)
        int n = P / 3136, r = P % 3136;
        int hh = r / 56, ww = r % 56;
        bbase[j] = (unsigned)(((n * 74 + hh) * 56 + ww) * 512) + (unsigned)segp * 16u;
    }
    const char* w4c = (const char*)w4b;
    const char* t2c = (const char*)t2p;

#define STAGE(kk_, boff_) do {                                                        \
    unsigned _ao = (unsigned)(kk_) * 128u;                                            \
    unsigned _bo = (unsigned)((kk_) >> 2) * 86016u + (unsigned)((kk_) & 3) * 128u;    \
    _Pragma("unroll")                                                                 \
    for (int _j = 0; _j < 4; ++_j)                                                    \
        __builtin_amdgcn_global_load_lds((const AS1 void*)(w4c + abase[_j] + _ao),    \
            (AS3 void*)(lds + (boff_) + _j * 8192 + wv * 1024), 16, 0, 0);            \
    _Pragma("unroll")                                                                 \
    for (int _j = 0; _j < 4; ++_j)                                                    \
        __builtin_amdgcn_global_load_lds((const AS1 void*)(t2c + bbase[_j] + _bo),    \
            (AS3 void*)(lds + (boff_) + 32768 + _j * 8192 + wv * 1024), 16, 0, 0);    \
} while (0)

    // ---- fragment-read constants ----
    const int lr = l & 15, lg = l >> 4;
    const int sx = lr & 7;
    const unsigned fo0 = (unsigned)((lg ^ sx) << 4);
    const unsigned fo1 = (unsigned)(((lg + 4) ^ sx) << 4);
    const unsigned aRow = (unsigned)(wc * 8192 + lr * 128);            // + nn*2048
    const unsigned bRow = (unsigned)(32768 + wr * 16384 + lr * 128);   // + m*2048

    f32x4 acc[8][4];
    #pragma unroll
    for (int m = 0; m < 8; ++m)
        #pragma unroll
        for (int nn = 0; nn < 4; ++nn)
            acc[m][nn] = (f32x4){0.f, 0.f, 0.f, 0.f};

    bf16x8 afrag[4][2], bfrag[4][2];

    STAGE(0, 0);   // prologue: K-tile 0 -> buf0

    for (int kk = 0; kk < 28; ++kk) {
        const unsigned cur = (unsigned)(kk & 1) * 65536u;
        const unsigned nxt = cur ^ 65536u;
        const int kst = (kk < 27) ? kk + 1 : 27;  // last tile: redundant self-stage keeps vmcnt uniform

        // ========== phase 1: quadrant (pix half 0, o half 0) ==========
        STAGE(kst, nxt);
        asm volatile("s_waitcnt vmcnt(8)" ::: "memory");  // exactly tile-kk's 8 loads drained
        __builtin_amdgcn_s_barrier();                     // cross-wave: all stages landed
        asm volatile("" ::: "memory");
        #pragma unroll
        for (int m = 0; m < 4; ++m) {
            bfrag[m][0] = *(const bf16x8*)(lds + cur + bRow + m * 2048 + fo0);
            bfrag[m][1] = *(const bf16x8*)(lds + cur + bRow + m * 2048 + fo1);
        }
        #pragma unroll
        for (int nn = 0; nn < 2; ++nn) {
            afrag[nn][0] = *(const bf16x8*)(lds + cur + aRow + nn * 2048 + fo0);
            afrag[nn][1] = *(const bf16x8*)(lds + cur + aRow + nn * 2048 + fo1);
        }
        __builtin_amdgcn_s_setprio(1);
        #pragma unroll
        for (int m = 0; m < 4; ++m)
            #pragma unroll
            for (int nn = 0; nn < 2; ++nn) {
                acc[m][nn] = __builtin_amdgcn_mfma_f32_16x16x32_bf16(afrag[nn][0], bfrag[m][0], acc[m][nn], 0, 0, 0);
                acc[m][nn] = __builtin_amdgcn_mfma_f32_16x16x32_bf16(afrag[nn][1], bfrag[m][1], acc[m][nn], 0, 0, 0);
            }
        __builtin_amdgcn_s_setprio(0);
        __builtin_amdgcn_s_barrier();
        asm volatile("" ::: "memory");

        // ========== phase 2: (pix half 0, o half 1) — read a nn=2,3 ==========
        #pragma unroll
        for (int nn = 2; nn < 4; ++nn) {
            afrag[nn][0] = *(const bf16x8*)(lds + cur + aRow + nn * 2048 + fo0);
            afrag[nn][1] = *(const bf16x8*)(lds + cur + aRow + nn * 2048 + fo1);
        }
        __builtin_amdgcn_s_setprio(1);
        #pragma unroll
        for (int m = 0; m < 4; ++m)
            #pragma unroll
            for (int nn = 2; nn < 4; ++nn) {
                acc[m][nn] = __builtin_amdgcn_mfma_f32_16x16x32_bf16(afrag[nn][0], bfrag[m][0], acc[m][nn], 0, 0, 0);
                acc[m][nn] = __builtin_amdgcn_mfma_f32_16x16x32_bf16(afrag[nn][1], bfrag[m][1], acc[m][nn], 0, 0, 0);
            }
        __builtin_amdgcn_s_setprio(0);
        __builtin_amdgcn_s_barrier();
        asm volatile("" ::: "memory");

        // ========== phase 3: (pix half 1, o half 1) — read b m=4..7 ==========
        #pragma unroll
        for (int mb = 0; mb < 4; ++mb) {
            bfrag[mb][0] = *(const bf16x8*)(lds + cur + bRow + (4 + mb) * 2048 + fo0);
            bfrag[mb][1] = *(const bf16x8*)(lds + cur + bRow + (4 + mb) * 2048 + fo1);
        }
        __builtin_amdgcn_s_setprio(1);
        #pragma unroll
        for (int mb = 0; mb < 4; ++mb)
            #pragma unroll
            for (int nn = 2; nn < 4; ++nn) {
                acc[4 + mb][nn] = __builtin_amdgcn_mfma_f32_16x16x32_bf16(afrag[nn][0], bfrag[mb][0], acc[4 + mb][nn], 0, 0, 0);
                acc[4 + mb][nn] = __builtin_amdgcn_mfma_f32_16x16x32_bf16(afrag[nn][1], bfrag[mb][1], acc[4 + mb][nn], 0, 0, 0);
            }
        __builtin_amdgcn_s_setprio(0);
        __builtin_amdgcn_s_barrier();
        asm volatile("" ::: "memory");

        // ========== phase 4: (pix half 1, o half 0) — no new reads ==========
        __builtin_amdgcn_s_setprio(1);
        #pragma unroll
        for (int mb = 0; mb < 4; ++mb)
            #pragma unroll
            for (int nn = 0; nn < 2; ++nn) {
                acc[4 + mb][nn] = __builtin_amdgcn_mfma_f32_16x16x32_bf16(afrag[nn][0], bfrag[mb][0], acc[4 + mb][nn], 0, 0, 0);
                acc[4 + mb][nn] = __builtin_amdgcn_mfma_f32_16x16x32_bf16(afrag[nn][1], bfrag[mb][1], acc[4 + mb][nn], 0, 0, 0);
            }
        __builtin_amdgcn_s_setprio(0);
        __builtin_amdgcn_s_barrier();       // protects buf^1 before next p1 overwrites it
        asm volatile("" ::: "memory");
    }
#undef STAGE

    // ---- epilogue: C/D layout col(pix)=lane&15, row(o)=(lane>>4)*4+j; out = acc * t1 ----
    #pragma unroll
    for (int m = 0; m < 8; ++m) {
        int P = pix0 + wr * 128 + m * 16 + lr;
        int n = P / 3136, p = P % 3136;
        float* obase = out + (size_t)n * 802816 + p;
        #pragma unroll
        for (int nn = 0; nn < 4; ++nn) {
            int o = wc * 64 + nn * 16 + lg * 4;
            float* op = obase + (size_t)o * 3136;
            float t10 = op[0 * 3136];
            float t11 = op[1 * 3136];
            float t12 = op[2 * 3136];
            float t13 = op[3 * 3136];
            op[0 * 3136] = acc[m][nn][0] * t10;
            op[1 * 3136] = acc[m][nn][1] * t11;
            op[2 * 3136] = acc[m][nn][2] * t12;
            op[3 * 3136] = acc[m][nn][3] * t13;
        }
    }
}

// ---------------- kernel 3: t1 = depthwise 5x5 conv of x, written INTO d_out ------------
// (runs BEFORE k_gemm8; gemm epilogue multiplies acc by this value)
__global__ __launch_bounds__(256) void k_t1(const float* __restrict__ x,
                                            const float* __restrict__ w1,
                                            float* __restrict__ out) {
    const int b = blockIdx.x;
    const int c = b & 255, n = b >> 8;
    const int t = threadIdx.x;
    __shared__ float xs[60][60];

    float* lp = &xs[0][0];
    #pragma unroll
    for (int i = 0; i < 15; ++i) {
        int idx = t + i * 256;
        if (idx < 3600) lp[idx] = 0.f;
    }
    __syncthreads();

    const float* xc = x + (size_t)(n * 256 + c) * 3136;
    #pragma unroll
    for (int k = 0; k < 4; ++k) {
        int j = t + k * 256;
        if (j < 784) {
            f32x4 v = *(const f32x4*)(xc + j * 4);
            int p = j * 4;
            int h = p / 56, w = p % 56;
            xs[h + 2][w + 2 + 0] = v[0];
            xs[h + 2][w + 2 + 1] = v[1];
            xs[h + 2][w + 2 + 2] = v[2];
            xs[h + 2][w + 2 + 3] = v[3];
        }
    }

    const float* wk = w1 + c * 25;
    float wr[25];
    #pragma unroll
    for (int i = 0; i < 25; ++i) wr[i] = wk[i];
    __syncthreads();

    float* oc = out + (size_t)(n * 256 + c) * 3136;
    #pragma unroll
    for (int k = 0; k < 4; ++k) {
        int j = t + k * 256;
        if (j < 784) {
            int p = j * 4;
            int h = p / 56, w = p % 56;
            f32x4 t1 = {0.f, 0.f, 0.f, 0.f};
            #pragma unroll
            for (int dy = 0; dy < 5; ++dy)
                #pragma unroll
                for (int dx = 0; dx < 5; ++dx) {
                    float wv = wr[dy * 5 + dx];
                    t1[0] = fmaf(wv, xs[h + dy][w + dx + 0], t1[0]);
                    t1[1] = fmaf(wv, xs[h + dy][w + dx + 1], t1[1]);
                    t1[2] = fmaf(wv, xs[h + dy][w + dx + 2], t1[2]);
                    t1[3] = fmaf(wv, xs[h + dy][w + dx + 3], t1[3]);
                }
            *(f32x4*)(oc + p) = t1;
        }
    }
}

extern "C" void kernel_launch(void* const* d_in, const int* in_sizes, int n_in,
                              void* d_out, int out_size, void* d_ws, size_t ws_size,
                              hipStream_t stream) {
    const float* x  = (const float*)d_in[0];
    const float* w1 = (const float*)d_in[1];
    const float* w2 = (const float*)d_in[2];
    const float* w4 = (const float*)d_in[3];
    float* out = (float*)d_out;

    const size_t W4B_ELEMS = 256 * 1792;
    const size_t T2P_ELEMS = (size_t)16 * 74 * 56 * 256;
    if (ws_size < (W4B_ELEMS + T2P_ELEMS) * sizeof(unsigned short)) return;
    unsigned short* w4b = (unsigned short*)d_ws;
    unsigned short* t2p = w4b + W4B_ELEMS;

    k_w4conv<<<1792, 256, 0, stream>>>(w4, w4b);
    k_t1<<<4096, 256, 0, stream>>>(x, w1, out);
    k_t2prep<<<16 * 74, 256, 0, stream>>>(x, w2, t2p);
    k_gemm8<<<196, 512, 131072, stream>>>(w4b, t2p, out);
}

// Round 8
// 147.372 us; speedup vs baseline: 1.0627x; 1.0627x over previous
//
#include <hip/hip_runtime.h>
#include <hip/hip_bf16.h>
#include <stdint.h>
#include <stddef.h>

#define AS1 __attribute__((address_space(1)))
#define AS3 __attribute__((address_space(3)))

typedef __attribute__((ext_vector_type(8))) __bf16 bf16x8;
typedef __attribute__((ext_vector_type(4))) float f32x4;
typedef __attribute__((ext_vector_type(4))) unsigned int u32x4;

static __device__ __forceinline__ unsigned short f2bf(float f) {
    unsigned u = __builtin_bit_cast(unsigned, f);
    u += 0x7FFFu + ((u >> 16) & 1u);
    return (unsigned short)(u >> 16);
}

// ---------------- kernel 1: t2 = depthwise (3,1) conv, store NHWC bf16, H padded by 9 ----
__global__ void k_t2prep(const float* __restrict__ x, const float* __restrict__ w2,
                         unsigned short* __restrict__ t2p) {
    const int b = blockIdx.x;
    const int n = b / 74, hp = b % 74;
    const int t = threadIdx.x;
    unsigned short* orow = t2p + (size_t)(n * 74 + hp) * (56 * 256);
    const int h = hp - 9;
    if (h < 0 || h >= 56) {
        u32x4 z = {0u, 0u, 0u, 0u};
        #pragma unroll
        for (int i = 0; i < 7; ++i)
            *(u32x4*)(orow + (size_t)(i * 256 + t) * 8) = z;
        return;
    }
    __shared__ float xs[3][64][57];
    __shared__ float w2s[64][3];
    for (int cc = 0; cc < 256; cc += 64) {
        if (cc) __syncthreads();
        if (t < 192) w2s[t / 3][t % 3] = w2[(cc + t / 3) * 3 + (t % 3)];
        for (int idx = t; idx < 2688; idx += 256) {
            int r = idx / 896, rem = idx % 896;
            int ci = rem / 14, q = rem % 14;
            int hy = h - 1 + r;
            f32x4 v = {0.f, 0.f, 0.f, 0.f};
            if (hy >= 0 && hy < 56)
                v = *(const f32x4*)(x + (size_t)((n * 256 + cc + ci) * 56 + hy) * 56 + q * 4);
            xs[r][ci][q * 4 + 0] = v[0];
            xs[r][ci][q * 4 + 1] = v[1];
            xs[r][ci][q * 4 + 2] = v[2];
            xs[r][ci][q * 4 + 3] = v[3];
        }
        __syncthreads();
        const int c = t & 63;
        const float a0 = w2s[c][0], a1 = w2s[c][1], a2 = w2s[c][2];
        #pragma unroll
        for (int i = 0; i < 14; ++i) {
            int w = i * 4 + (t >> 6);
            float v = a0 * xs[0][c][w] + a1 * xs[1][c][w] + a2 * xs[2][c][w];
            orow[w * 256 + cc + c] = f2bf(v);
        }
    }
}

// ---------------- kernel 1b: w4 reorder + bf16 convert: w4b[o][k*256+c] = w4[o][c*7+k] ----
__global__ void k_w4conv(const float* __restrict__ w4, unsigned short* __restrict__ w4b) {
    int tid = blockIdx.x * 256 + threadIdx.x;
    int o = tid / 1792, j = tid % 1792;
    int k = j >> 8, c = j & 255;
    w4b[tid] = f2bf(w4[o * 1792 + c * 7 + k]);
}

// ---------------- kernel 2: 256x256 GEMM, round-3 skeleton, 2 barriers per K-tile -------
// A = w4b [256 o x 1792 K], B[K][pix] from t2p NHWC. BK=64, 28 K-tiles, dbuf LDS 128KB.
// Per tile: {STAGE(t+1)->nxt; vmcnt(8); barrier; read frags + 64 MFMA; barrier}.
// Hazards (r3 proof): end-of-tile barrier -> all waves' reads of cur done before iter
// t+1 stages into it; per-wave vmcnt(8) before 1st barrier -> stage(t) fully landed.
__global__ __launch_bounds__(512, 2) void k_gemm8(const unsigned short* __restrict__ w4b,
                                                  const unsigned short* __restrict__ t2p,
                                                  float* __restrict__ out) {
    extern __shared__ char lds[];                 // 131072 B: [buf][A 32K | B 32K]
    const int pix0 = blockIdx.x * 256;
    const int t = threadIdx.x;
    const int l = t & 63, wv = t >> 6;
    const int wr = wv >> 2, wc = wv & 3;

    // ---- staging bases (bytes), pre-swizzled source (rule 21 involution) ----
    const int srow = t >> 3;                      // 0..63 within a 64-row load
    const int segp = (t & 7) ^ (srow & 7);
    unsigned abase[4], bbase[4];
    #pragma unroll
    for (int j = 0; j < 4; ++j) {
        int arow = j * 64 + srow;                 // o row
        abase[j] = (unsigned)arow * 3584u + (unsigned)segp * 16u;
        int P = pix0 + j * 64 + srow;             // pixel row (always < 50176)
        int n = P / 3136, r = P % 3136;
        int hh = r / 56, ww = r % 56;
        bbase[j] = (unsigned)(((n * 74 + hh) * 56 + ww) * 512) + (unsigned)segp * 16u;
    }
    const char* w4c = (const char*)w4b;
    const char* t2c = (const char*)t2p;

#define STAGE(kk_, boff_) do {                                                        \
    unsigned _ao = (unsigned)(kk_) * 128u;                                            \
    unsigned _bo = (unsigned)((kk_) >> 2) * 86016u + (unsigned)((kk_) & 3) * 128u;    \
    _Pragma("unroll")                                                                 \
    for (int _j = 0; _j < 4; ++_j)                                                    \
        __builtin_amdgcn_global_load_lds((const AS1 void*)(w4c + abase[_j] + _ao),    \
            (AS3 void*)(lds + (boff_) + _j * 8192 + wv * 1024), 16, 0, 0);            \
    _Pragma("unroll")                                                                 \
    for (int _j = 0; _j < 4; ++_j)                                                    \
        __builtin_amdgcn_global_load_lds((const AS1 void*)(t2c + bbase[_j] + _bo),    \
            (AS3 void*)(lds + (boff_) + 32768 + _j * 8192 + wv * 1024), 16, 0, 0);    \
} while (0)

    // ---- fragment-read constants ----
    const int lr = l & 15, lg = l >> 4;
    const int sx = lr & 7;
    const unsigned fo0 = (unsigned)((lg ^ sx) << 4);
    const unsigned fo1 = (unsigned)(((lg + 4) ^ sx) << 4);
    const unsigned aRow = (unsigned)(wc * 8192 + lr * 128);            // + nn*2048
    const unsigned bRow = (unsigned)(32768 + wr * 16384 + lr * 128);   // + m*2048

    f32x4 acc[8][4];
    #pragma unroll
    for (int m = 0; m < 8; ++m)
        #pragma unroll
        for (int nn = 0; nn < 4; ++nn)
            acc[m][nn] = (f32x4){0.f, 0.f, 0.f, 0.f};

    bf16x8 afrag[4][2];

// one B-chunk: 2 B rows (16 transient VGPRs), 16 MFMAs against all 4 A-frags
#define BCHUNK(M0_, CUR_) do {                                                         \
    bf16x8 _b00 = *(const bf16x8*)(lds + (CUR_) + bRow + (M0_) * 2048 + fo0);          \
    bf16x8 _b01 = *(const bf16x8*)(lds + (CUR_) + bRow + (M0_) * 2048 + fo1);          \
    bf16x8 _b10 = *(const bf16x8*)(lds + (CUR_) + bRow + ((M0_) + 1) * 2048 + fo0);    \
    bf16x8 _b11 = *(const bf16x8*)(lds + (CUR_) + bRow + ((M0_) + 1) * 2048 + fo1);    \
    __builtin_amdgcn_s_setprio(1);                                                     \
    _Pragma("unroll")                                                                  \
    for (int _n = 0; _n < 4; ++_n) {                                                   \
        acc[(M0_)][_n]     = __builtin_amdgcn_mfma_f32_16x16x32_bf16(afrag[_n][0], _b00, acc[(M0_)][_n], 0, 0, 0);     \
        acc[(M0_)][_n]     = __builtin_amdgcn_mfma_f32_16x16x32_bf16(afrag[_n][1], _b01, acc[(M0_)][_n], 0, 0, 0);     \
        acc[(M0_) + 1][_n] = __builtin_amdgcn_mfma_f32_16x16x32_bf16(afrag[_n][0], _b10, acc[(M0_) + 1][_n], 0, 0, 0); \
        acc[(M0_) + 1][_n] = __builtin_amdgcn_mfma_f32_16x16x32_bf16(afrag[_n][1], _b11, acc[(M0_) + 1][_n], 0, 0, 0); \
    }                                                                                  \
    __builtin_amdgcn_s_setprio(0);                                                     \
} while (0)

    STAGE(0, 0);   // prologue: K-tile 0 -> buf0

    for (int kk = 0; kk < 28; ++kk) {
        const unsigned cur = (unsigned)(kk & 1) * 65536u;
        const unsigned nxt = cur ^ 65536u;
        const int kst = (kk < 27) ? kk + 1 : 27;  // last tile: redundant self-stage keeps vmcnt uniform

        STAGE(kst, nxt);
        asm volatile("s_waitcnt vmcnt(8)" ::: "memory");  // exactly tile-kk's 8 loads drained
        __builtin_amdgcn_s_barrier();                     // cross-wave: all stages landed
        asm volatile("" ::: "memory");

        // read all 4 A-frags for this tile (32 VGPRs, live across the tile)
        #pragma unroll
        for (int nn = 0; nn < 4; ++nn) {
            afrag[nn][0] = *(const bf16x8*)(lds + cur + aRow + nn * 2048 + fo0);
            afrag[nn][1] = *(const bf16x8*)(lds + cur + aRow + nn * 2048 + fo1);
        }
        // 4 chunks x (2 B rows + 16 MFMAs); no intra-tile barriers
        BCHUNK(0, cur);
        BCHUNK(2, cur);
        BCHUNK(4, cur);
        BCHUNK(6, cur);

        __builtin_amdgcn_s_barrier();       // all reads of cur done before next overwrite
        asm volatile("" ::: "memory");
    }
#undef BCHUNK
#undef STAGE

    // ---- epilogue: C/D layout col(pix)=lane&15, row(o)=(lane>>4)*4+j ----
    #pragma unroll
    for (int m = 0; m < 8; ++m) {
        int P = pix0 + wr * 128 + m * 16 + lr;
        int n = P / 3136, p = P % 3136;
        float* ob = out + (size_t)n * 802816 + p;
        #pragma unroll
        for (int nn = 0; nn < 4; ++nn) {
            int o = wc * 64 + nn * 16 + lg * 4;
            float* op = ob + (size_t)o * 3136;
            op[0 * 3136] = acc[m][nn][0];
            op[1 * 3136] = acc[m][nn][1];
            op[2 * 3136] = acc[m][nn][2];
            op[3 * 3136] = acc[m][nn][3];
        }
    }
}

// ---------------- kernel 3: out *= t1 (depthwise 5x5, LDS-tiled per (n,c) plane) --------
__global__ __launch_bounds__(256) void k_gate(const float* __restrict__ x,
                                              const float* __restrict__ w1,
                                              float* __restrict__ out) {
    const int b = blockIdx.x;
    const int c = b & 255, n = b >> 8;
    const int t = threadIdx.x;
    __shared__ float xs[60][60];

    float* lp = &xs[0][0];
    #pragma unroll
    for (int i = 0; i < 15; ++i) {
        int idx = t + i * 256;
        if (idx < 3600) lp[idx] = 0.f;
    }
    __syncthreads();

    const float* xc = x + (size_t)(n * 256 + c) * 3136;
    #pragma unroll
    for (int k = 0; k < 4; ++k) {
        int j = t + k * 256;
        if (j < 784) {
            f32x4 v = *(const f32x4*)(xc + j * 4);
            int p = j * 4;
            int h = p / 56, w = p % 56;
            xs[h + 2][w + 2 + 0] = v[0];
            xs[h + 2][w + 2 + 1] = v[1];
            xs[h + 2][w + 2 + 2] = v[2];
            xs[h + 2][w + 2 + 3] = v[3];
        }
    }

    const float* wk = w1 + c * 25;
    float wr[25];
    #pragma unroll
    for (int i = 0; i < 25; ++i) wr[i] = wk[i];
    __syncthreads();

    float* oc = out + (size_t)(n * 256 + c) * 3136;
    #pragma unroll
    for (int k = 0; k < 4; ++k) {
        int j = t + k * 256;
        if (j < 784) {
            int p = j * 4;
            int h = p / 56, w = p % 56;
            f32x4 o = *(f32x4*)(oc + p);
            f32x4 t1 = {0.f, 0.f, 0.f, 0.f};
            #pragma unroll
            for (int dy = 0; dy < 5; ++dy)
                #pragma unroll
                for (int dx = 0; dx < 5; ++dx) {
                    float wv = wr[dy * 5 + dx];
                    t1[0] = fmaf(wv, xs[h + dy][w + dx + 0], t1[0]);
                    t1[1] = fmaf(wv, xs[h + dy][w + dx + 1], t1[1]);
                    t1[2] = fmaf(wv, xs[h + dy][w + dx + 2], t1[2]);
                    t1[3] = fmaf(wv, xs[h + dy][w + dx + 3], t1[3]);
                }
            o *= t1;
            *(f32x4*)(oc + p) = o;
        }
    }
}

extern "C" void kernel_launch(void* const* d_in, const int* in_sizes, int n_in,
                              void* d_out, int out_size, void* d_ws, size_t ws_size,
                              hipStream_t stream) {
    const float* x  = (const float*)d_in[0];
    const float* w1 = (const float*)d_in[1];
    const float* w2 = (const float*)d_in[2];
    const float* w4 = (const float*)d_in[3];
    float* out = (float*)d_out;

    const size_t W4B_ELEMS = 256 * 1792;
    const size_t T2P_ELEMS = (size_t)16 * 74 * 56 * 256;
    if (ws_size < (W4B_ELEMS + T2P_ELEMS) * sizeof(unsigned short)) return;
    unsigned short* w4b = (unsigned short*)d_ws;
    unsigned short* t2p = w4b + W4B_ELEMS;

    k_w4conv<<<1792, 256, 0, stream>>>(w4, w4b);
    k_t2prep<<<16 * 74, 256, 0, stream>>>(x, w2, t2p);
    k_gemm8<<<196, 512, 131072, stream>>>(w4b, t2p, out);
    k_gate<<<4096, 256, 0, stream>>>(x, w1, out);
}

// Round 9
// 143.880 us; speedup vs baseline: 1.0885x; 1.0243x over previous
//
#include <hip/hip_runtime.h>
#include <hip/hip_bf16.h>
#include <stdint.h>
#include <stddef.h>

#define AS1 __attribute__((address_space(1)))
#define AS3 __attribute__((address_space(3)))

typedef __attribute__((ext_vector_type(8))) __bf16 bf16x8;
typedef __attribute__((ext_vector_type(4))) float f32x4;
typedef __attribute__((ext_vector_type(4))) unsigned int u32x4;

static __device__ __forceinline__ unsigned short f2bf(float f) {
    unsigned u = __builtin_bit_cast(unsigned, f);
    u += 0x7FFFu + ((u >> 16) & 1u);
    return (unsigned short)(u >> 16);
}

// ---------------- kernel 1: t2 = depthwise (3,1) conv, store NHWC bf16, H padded by 9 ----
__global__ void k_t2prep(const float* __restrict__ x, const float* __restrict__ w2,
                         unsigned short* __restrict__ t2p) {
    const int b = blockIdx.x;
    const int n = b / 74, hp = b % 74;
    const int t = threadIdx.x;
    unsigned short* orow = t2p + (size_t)(n * 74 + hp) * (56 * 256);
    const int h = hp - 9;
    if (h < 0 || h >= 56) {
        u32x4 z = {0u, 0u, 0u, 0u};
        #pragma unroll
        for (int i = 0; i < 7; ++i)
            *(u32x4*)(orow + (size_t)(i * 256 + t) * 8) = z;
        return;
    }
    __shared__ float xs[3][64][57];
    __shared__ float w2s[64][3];
    for (int cc = 0; cc < 256; cc += 64) {
        if (cc) __syncthreads();
        if (t < 192) w2s[t / 3][t % 3] = w2[(cc + t / 3) * 3 + (t % 3)];
        for (int idx = t; idx < 2688; idx += 256) {
            int r = idx / 896, rem = idx % 896;
            int ci = rem / 14, q = rem % 14;
            int hy = h - 1 + r;
            f32x4 v = {0.f, 0.f, 0.f, 0.f};
            if (hy >= 0 && hy < 56)
                v = *(const f32x4*)(x + (size_t)((n * 256 + cc + ci) * 56 + hy) * 56 + q * 4);
            xs[r][ci][q * 4 + 0] = v[0];
            xs[r][ci][q * 4 + 1] = v[1];
            xs[r][ci][q * 4 + 2] = v[2];
            xs[r][ci][q * 4 + 3] = v[3];
        }
        __syncthreads();
        const int c = t & 63;
        const float a0 = w2s[c][0], a1 = w2s[c][1], a2 = w2s[c][2];
        #pragma unroll
        for (int i = 0; i < 14; ++i) {
            int w = i * 4 + (t >> 6);
            float v = a0 * xs[0][c][w] + a1 * xs[1][c][w] + a2 * xs[2][c][w];
            orow[w * 256 + cc + c] = f2bf(v);
        }
    }
}

// ---------------- kernel 1b: w4 reorder + bf16 convert: w4b[o][k*256+c] = w4[o][c*7+k] ----
__global__ void k_w4conv(const float* __restrict__ w4, unsigned short* __restrict__ w4b) {
    int tid = blockIdx.x * 256 + threadIdx.x;
    int o = tid / 1792, j = tid % 1792;
    int k = j >> 8, c = j & 255;
    w4b[tid] = f2bf(w4[o * 1792 + c * 7 + k]);
}

// ---------------- kernel 2: 224pix x 256o GEMM, r8 body, 224 blocks (87.5% CU fill) ----
// A = w4b [256 o x 1792 K], B[K][pix] from t2p NHWC. BK=64, 28 K-tiles.
// LDS: 2 bufs x (A 32KB + B 28KB) = 122880 B. B staged via 16B slot map:
// slots 0..1791 (row = s>>3, seg = s&7, swizzled seg' = seg ^ (row&7)); ops 0-2 by all
// 512 threads, op 3 by t<256 -> per-wave uniform VMEM: waves 0-3 = 8 ops, 4-7 = 7 ops.
// Counted drain: after STAGE(t+1), own outstanding = 2x own ops; vmcnt(own) => tile t landed.
__global__ __launch_bounds__(512, 2) void k_gemm8(const unsigned short* __restrict__ w4b,
                                                  const unsigned short* __restrict__ t2p,
                                                  float* __restrict__ out) {
    extern __shared__ char lds[];                 // 122880 B
    const int pix0 = blockIdx.x * 224;
    const int t = threadIdx.x;
    const int l = t & 63, wv = t >> 6;
    const int wr = wv >> 2, wc = wv & 3;
    const bool doB4 = (wv < 4);                   // wave-uniform

    // ---- A staging source bases (o rows, 4 x 64-row groups, pre-swizzled seg) ----
    const char* w4c = (const char*)w4b;
    const char* t2c = (const char*)t2p;
    unsigned abase[4];
    {
        const int srow = t >> 3;                  // 0..63
        const int segp = (t & 7) ^ (srow & 7);
        #pragma unroll
        for (int j = 0; j < 4; ++j)
            abase[j] = (unsigned)(j * 64 + srow) * 3584u + (unsigned)segp * 16u;
    }
    // ---- B staging source bases via slot map ----
    unsigned bbase[4];
    #pragma unroll
    for (int o = 0; o < 4; ++o) {
        int s = (o < 3) ? (t + (o << 9)) : (1536 + (t & 255));  // t&255: dummy for wv>=4 (unissued)
        int row = s >> 3;
        int segp = (s & 7) ^ (row & 7);
        int P = pix0 + row;                       // row <= 223 -> P <= 50175
        int n = P / 3136, rr = P % 3136;
        int hh = rr / 56, ww = rr % 56;
        bbase[o] = (unsigned)(((n * 74 + hh) * 56 + ww) * 512) + (unsigned)segp * 16u;
    }

#define STAGE(kk_, boff_) do {                                                        \
    unsigned _ao = (unsigned)(kk_) * 128u;                                            \
    unsigned _bo = (unsigned)((kk_) >> 2) * 86016u + (unsigned)((kk_) & 3) * 128u;    \
    _Pragma("unroll")                                                                 \
    for (int _j = 0; _j < 4; ++_j)                                                    \
        __builtin_amdgcn_global_load_lds((const AS1 void*)(w4c + abase[_j] + _ao),    \
            (AS3 void*)(lds + (boff_) + _j * 8192 + wv * 1024), 16, 0, 0);            \
    _Pragma("unroll")                                                                 \
    for (int _o = 0; _o < 3; ++_o)                                                    \
        __builtin_amdgcn_global_load_lds((const AS1 void*)(t2c + bbase[_o] + _bo),    \
            (AS3 void*)(lds + (boff_) + 32768 + _o * 8192 + wv * 1024), 16, 0, 0);    \
    if (doB4)                                                                         \
        __builtin_amdgcn_global_load_lds((const AS1 void*)(t2c + bbase[3] + _bo),     \
            (AS3 void*)(lds + (boff_) + 32768 + 24576 + wv * 1024), 16, 0, 0);        \
} while (0)

    // ---- fragment-read constants (XOR involution; row&7 == lr&7 for A and B) ----
    const int lr = l & 15, lg = l >> 4;
    const int sx = lr & 7;
    const unsigned fo0 = (unsigned)((lg ^ sx) << 4);
    const unsigned fo1 = (unsigned)(((lg + 4) ^ sx) << 4);
    const unsigned aRow = (unsigned)(wc * 8192 + lr * 128);            // + nn*2048
    const unsigned bRow = (unsigned)(32768 + wr * 14336 + lr * 128);   // + m*2048

    f32x4 acc[7][4];
    #pragma unroll
    for (int m = 0; m < 7; ++m)
        #pragma unroll
        for (int nn = 0; nn < 4; ++nn)
            acc[m][nn] = (f32x4){0.f, 0.f, 0.f, 0.f};

    bf16x8 afrag[4][2];

// one B-chunk: 2 B rows (16 transient VGPRs), 16 MFMAs against all 4 A-frags
#define BCHUNK(M0_, CUR_) do {                                                         \
    bf16x8 _b00 = *(const bf16x8*)(lds + (CUR_) + bRow + (M0_) * 2048 + fo0);          \
    bf16x8 _b01 = *(const bf16x8*)(lds + (CUR_) + bRow + (M0_) * 2048 + fo1);          \
    bf16x8 _b10 = *(const bf16x8*)(lds + (CUR_) + bRow + ((M0_) + 1) * 2048 + fo0);    \
    bf16x8 _b11 = *(const bf16x8*)(lds + (CUR_) + bRow + ((M0_) + 1) * 2048 + fo1);    \
    __builtin_amdgcn_s_setprio(1);                                                     \
    _Pragma("unroll")                                                                  \
    for (int _n = 0; _n < 4; ++_n) {                                                   \
        acc[(M0_)][_n]     = __builtin_amdgcn_mfma_f32_16x16x32_bf16(afrag[_n][0], _b00, acc[(M0_)][_n], 0, 0, 0);     \
        acc[(M0_)][_n]     = __builtin_amdgcn_mfma_f32_16x16x32_bf16(afrag[_n][1], _b01, acc[(M0_)][_n], 0, 0, 0);     \
        acc[(M0_) + 1][_n] = __builtin_amdgcn_mfma_f32_16x16x32_bf16(afrag[_n][0], _b10, acc[(M0_) + 1][_n], 0, 0, 0); \
        acc[(M0_) + 1][_n] = __builtin_amdgcn_mfma_f32_16x16x32_bf16(afrag[_n][1], _b11, acc[(M0_) + 1][_n], 0, 0, 0); \
    }                                                                                  \
    __builtin_amdgcn_s_setprio(0);                                                     \
} while (0)

    STAGE(0, 0);   // prologue: K-tile 0 -> buf0

    for (int kk = 0; kk < 28; ++kk) {
        const unsigned cur = (kk & 1) ? 61440u : 0u;
        const unsigned nxt = cur ^ 61440u;
        const int kst = (kk < 27) ? kk + 1 : 27;  // last tile: redundant self-stage keeps counts uniform

        STAGE(kst, nxt);
        if (doB4) { asm volatile("s_waitcnt vmcnt(8)" ::: "memory"); }
        else      { asm volatile("s_waitcnt vmcnt(7)" ::: "memory"); }
        __builtin_amdgcn_s_barrier();             // cross-wave: all stages landed
        asm volatile("" ::: "memory");

        // read all 4 A-frags for this tile (32 VGPRs, live across the tile)
        #pragma unroll
        for (int nn = 0; nn < 4; ++nn) {
            afrag[nn][0] = *(const bf16x8*)(lds + cur + aRow + nn * 2048 + fo0);
            afrag[nn][1] = *(const bf16x8*)(lds + cur + aRow + nn * 2048 + fo1);
        }
        // 3 chunks x (2 B rows + 16 MFMAs) + 1 single-row chunk (m=6)
        BCHUNK(0, cur);
        BCHUNK(2, cur);
        BCHUNK(4, cur);
        {
            bf16x8 _b60 = *(const bf16x8*)(lds + cur + bRow + 6 * 2048 + fo0);
            bf16x8 _b61 = *(const bf16x8*)(lds + cur + bRow + 6 * 2048 + fo1);
            __builtin_amdgcn_s_setprio(1);
            #pragma unroll
            for (int _n = 0; _n < 4; ++_n) {
                acc[6][_n] = __builtin_amdgcn_mfma_f32_16x16x32_bf16(afrag[_n][0], _b60, acc[6][_n], 0, 0, 0);
                acc[6][_n] = __builtin_amdgcn_mfma_f32_16x16x32_bf16(afrag[_n][1], _b61, acc[6][_n], 0, 0, 0);
            }
            __builtin_amdgcn_s_setprio(0);
        }

        __builtin_amdgcn_s_barrier();       // all reads of cur done before next overwrite
        asm volatile("" ::: "memory");
    }
#undef BCHUNK
#undef STAGE

    // ---- epilogue: C/D layout col(pix)=lane&15, row(o)=(lane>>4)*4+j ----
    #pragma unroll
    for (int m = 0; m < 7; ++m) {
        int P = pix0 + wr * 112 + m * 16 + lr;
        int n = P / 3136, p = P % 3136;
        float* ob = out + (size_t)n * 802816 + p;
        #pragma unroll
        for (int nn = 0; nn < 4; ++nn) {
            int o = wc * 64 + nn * 16 + lg * 4;
            float* op = ob + (size_t)o * 3136;
            op[0 * 3136] = acc[m][nn][0];
            op[1 * 3136] = acc[m][nn][1];
            op[2 * 3136] = acc[m][nn][2];
            op[3 * 3136] = acc[m][nn][3];
        }
    }
}

// ---------------- kernel 3: out *= t1 (depthwise 5x5, LDS-tiled per (n,c) plane) --------
__global__ __launch_bounds__(256) void k_gate(const float* __restrict__ x,
                                              const float* __restrict__ w1,
                                              float* __restrict__ out) {
    const int b = blockIdx.x;
    const int c = b & 255, n = b >> 8;
    const int t = threadIdx.x;
    __shared__ float xs[60][60];

    float* lp = &xs[0][0];
    #pragma unroll
    for (int i = 0; i < 15; ++i) {
        int idx = t + i * 256;
        if (idx < 3600) lp[idx] = 0.f;
    }
    __syncthreads();

    const float* xc = x + (size_t)(n * 256 + c) * 3136;
    #pragma unroll
    for (int k = 0; k < 4; ++k) {
        int j = t + k * 256;
        if (j < 784) {
            f32x4 v = *(const f32x4*)(xc + j * 4);
            int p = j * 4;
            int h = p / 56, w = p % 56;
            xs[h + 2][w + 2 + 0] = v[0];
            xs[h + 2][w + 2 + 1] = v[1];
            xs[h + 2][w + 2 + 2] = v[2];
            xs[h + 2][w + 2 + 3] = v[3];
        }
    }

    const float* wk = w1 + c * 25;
    float wr[25];
    #pragma unroll
    for (int i = 0; i < 25; ++i) wr[i] = wk[i];
    __syncthreads();

    float* oc = out + (size_t)(n * 256 + c) * 3136;
    #pragma unroll
    for (int k = 0; k < 4; ++k) {
        int j = t + k * 256;
        if (j < 784) {
            int p = j * 4;
            int h = p / 56, w = p % 56;
            f32x4 o = *(f32x4*)(oc + p);
            f32x4 t1 = {0.f, 0.f, 0.f, 0.f};
            #pragma unroll
            for (int dy = 0; dy < 5; ++dy)
                #pragma unroll
                for (int dx = 0; dx < 5; ++dx) {
                    float wv = wr[dy * 5 + dx];
                    t1[0] = fmaf(wv, xs[h + dy][w + dx + 0], t1[0]);
                    t1[1] = fmaf(wv, xs[h + dy][w + dx + 1], t1[1]);
                    t1[2] = fmaf(wv, xs[h + dy][w + dx + 2], t1[2]);
                    t1[3] = fmaf(wv, xs[h + dy][w + dx + 3], t1[3]);
                }
            o *= t1;
            *(f32x4*)(oc + p) = o;
        }
    }
}

extern "C" void kernel_launch(void* const* d_in, const int* in_sizes, int n_in,
                              void* d_out, int out_size, void* d_ws, size_t ws_size,
                              hipStream_t stream) {
    const float* x  = (const float*)d_in[0];
    const float* w1 = (const float*)d_in[1];
    const float* w2 = (const float*)d_in[2];
    const float* w4 = (const float*)d_in[3];
    float* out = (float*)d_out;

    const size_t W4B_ELEMS = 256 * 1792;
    const size_t T2P_ELEMS = (size_t)16 * 74 * 56 * 256;
    if (ws_size < (W4B_ELEMS + T2P_ELEMS) * sizeof(unsigned short)) return;
    unsigned short* w4b = (unsigned short*)d_ws;
    unsigned short* t2p = w4b + W4B_ELEMS;

    k_w4conv<<<1792, 256, 0, stream>>>(w4, w4b);
    k_t2prep<<<16 * 74, 256, 0, stream>>>(x, w2, t2p);
    k_gemm8<<<224, 512, 122880, stream>>>(w4b, t2p, out);
    k_gate<<<4096, 256, 0, stream>>>(x, w1, out);
}

// Round 10
// 113.973 us; speedup vs baseline: 1.3742x; 1.2624x over previous
//
#include <hip/hip_runtime.h>
#include <hip/hip_bf16.h>
#include <stdint.h>
#include <stddef.h>

#define AS1 __attribute__((address_space(1)))
#define AS3 __attribute__((address_space(3)))

typedef __attribute__((ext_vector_type(8))) __bf16 bf16x8;
typedef __attribute__((ext_vector_type(4))) float f32x4;
typedef __attribute__((ext_vector_type(4))) unsigned int u32x4;

static __device__ __forceinline__ unsigned short f2bf(float f) {
    unsigned u = __builtin_bit_cast(unsigned, f);
    u += 0x7FFFu + ((u >> 16) & 1u);
    return (unsigned short)(u >> 16);
}

// ---------------- kernel 1: t2 = depthwise (3,1) conv, NHWC bf16 out, H padded by 9 -----
// v2: block = (n, hp, 32-ch chunk). 9472 blocks, 22KB LDS -> 7 blocks/CU, 1 barrier.
__global__ __launch_bounds__(256) void k_t2prep(const float* __restrict__ x,
                                                const float* __restrict__ w2,
                                                unsigned short* __restrict__ t2p) {
    const int b = blockIdx.x;
    const int cc = (b & 7) * 32;
    const int hp = (b >> 3) % 74;
    const int n  = b / (74 * 8);
    const int t  = threadIdx.x;
    unsigned short* orow = t2p + (size_t)(n * 74 + hp) * (56 * 256);
    const int h = hp - 9;

    if (h < 0 || h >= 56) {
        // zero-fill this block's 32-ch slice: 56 w x 32 ch bf16 = 224 x u32x4
        if (t < 224) {
            int w = t >> 2, c8 = (t & 3) * 8;
            u32x4 z = {0u, 0u, 0u, 0u};
            *(u32x4*)(orow + (size_t)w * 256 + cc + c8) = z;
        }
        return;
    }

    __shared__ float xs[3][32][57];
    // load 3 rows x 32 ch x 56 w = 1344 float4
    for (int idx = t; idx < 1344; idx += 256) {
        int r = idx / 448, rem = idx % 448;
        int ci = rem / 14, q = rem % 14;
        int hy = h - 1 + r;
        f32x4 v = {0.f, 0.f, 0.f, 0.f};
        if (hy >= 0 && hy < 56)
            v = *(const f32x4*)(x + ((size_t)(n * 256 + cc + ci) * 56 + hy) * 56 + q * 4);
        xs[r][ci][q * 4 + 0] = v[0];
        xs[r][ci][q * 4 + 1] = v[1];
        xs[r][ci][q * 4 + 2] = v[2];
        xs[r][ci][q * 4 + 3] = v[3];
    }

    const int c = t & 31;
    const float a0 = w2[(cc + c) * 3 + 0];
    const float a1 = w2[(cc + c) * 3 + 1];
    const float a2 = w2[(cc + c) * 3 + 2];
    __syncthreads();

    #pragma unroll
    for (int i = 0; i < 7; ++i) {
        int w = (t >> 5) + i * 8;
        float v = a0 * xs[0][c][w] + a1 * xs[1][c][w] + a2 * xs[2][c][w];
        orow[(size_t)w * 256 + cc + c] = f2bf(v);
    }
}

// ---------------- kernel 1b: w4 reorder + bf16 convert: w4b[o][k*256+c] = w4[o][c*7+k] ----
__global__ void k_w4conv(const float* __restrict__ w4, unsigned short* __restrict__ w4b) {
    int tid = blockIdx.x * 256 + threadIdx.x;
    int o = tid / 1792, j = tid % 1792;
    int k = j >> 8, c = j & 255;
    w4b[tid] = f2bf(w4[o * 1792 + c * 7 + k]);
}

// ---------------- kernel 2: 224pix x 256o GEMM, r8 body, 224 blocks (87.5% CU fill) ----
__global__ __launch_bounds__(512, 2) void k_gemm8(const unsigned short* __restrict__ w4b,
                                                  const unsigned short* __restrict__ t2p,
                                                  float* __restrict__ out) {
    extern __shared__ char lds[];                 // 122880 B
    const int pix0 = blockIdx.x * 224;
    const int t = threadIdx.x;
    const int l = t & 63, wv = t >> 6;
    const int wr = wv >> 2, wc = wv & 3;
    const bool doB4 = (wv < 4);                   // wave-uniform

    const char* w4c = (const char*)w4b;
    const char* t2c = (const char*)t2p;
    unsigned abase[4];
    {
        const int srow = t >> 3;                  // 0..63
        const int segp = (t & 7) ^ (srow & 7);
        #pragma unroll
        for (int j = 0; j < 4; ++j)
            abase[j] = (unsigned)(j * 64 + srow) * 3584u + (unsigned)segp * 16u;
    }
    unsigned bbase[4];
    #pragma unroll
    for (int o = 0; o < 4; ++o) {
        int s = (o < 3) ? (t + (o << 9)) : (1536 + (t & 255));  // dummy for wv>=4 (unissued)
        int row = s >> 3;
        int segp = (s & 7) ^ (row & 7);
        int P = pix0 + row;
        int n = P / 3136, rr = P % 3136;
        int hh = rr / 56, ww = rr % 56;
        bbase[o] = (unsigned)(((n * 74 + hh) * 56 + ww) * 512) + (unsigned)segp * 16u;
    }

#define STAGE(kk_, boff_) do {                                                        \
    unsigned _ao = (unsigned)(kk_) * 128u;                                            \
    unsigned _bo = (unsigned)((kk_) >> 2) * 86016u + (unsigned)((kk_) & 3) * 128u;    \
    _Pragma("unroll")                                                                 \
    for (int _j = 0; _j < 4; ++_j)                                                    \
        __builtin_amdgcn_global_load_lds((const AS1 void*)(w4c + abase[_j] + _ao),    \
            (AS3 void*)(lds + (boff_) + _j * 8192 + wv * 1024), 16, 0, 0);            \
    _Pragma("unroll")                                                                 \
    for (int _o = 0; _o < 3; ++_o)                                                    \
        __builtin_amdgcn_global_load_lds((const AS1 void*)(t2c + bbase[_o] + _bo),    \
            (AS3 void*)(lds + (boff_) + 32768 + _o * 8192 + wv * 1024), 16, 0, 0);    \
    if (doB4)                                                                         \
        __builtin_amdgcn_global_load_lds((const AS1 void*)(t2c + bbase[3] + _bo),     \
            (AS3 void*)(lds + (boff_) + 32768 + 24576 + wv * 1024), 16, 0, 0);        \
} while (0)

    const int lr = l & 15, lg = l >> 4;
    const int sx = lr & 7;
    const unsigned fo0 = (unsigned)((lg ^ sx) << 4);
    const unsigned fo1 = (unsigned)(((lg + 4) ^ sx) << 4);
    const unsigned aRow = (unsigned)(wc * 8192 + lr * 128);            // + nn*2048
    const unsigned bRow = (unsigned)(32768 + wr * 14336 + lr * 128);   // + m*2048

    f32x4 acc[7][4];
    #pragma unroll
    for (int m = 0; m < 7; ++m)
        #pragma unroll
        for (int nn = 0; nn < 4; ++nn)
            acc[m][nn] = (f32x4){0.f, 0.f, 0.f, 0.f};

    bf16x8 afrag[4][2];

#define BCHUNK(M0_, CUR_) do {                                                         \
    bf16x8 _b00 = *(const bf16x8*)(lds + (CUR_) + bRow + (M0_) * 2048 + fo0);          \
    bf16x8 _b01 = *(const bf16x8*)(lds + (CUR_) + bRow + (M0_) * 2048 + fo1);          \
    bf16x8 _b10 = *(const bf16x8*)(lds + (CUR_) + bRow + ((M0_) + 1) * 2048 + fo0);    \
    bf16x8 _b11 = *(const bf16x8*)(lds + (CUR_) + bRow + ((M0_) + 1) * 2048 + fo1);    \
    __builtin_amdgcn_s_setprio(1);                                                     \
    _Pragma("unroll")                                                                  \
    for (int _n = 0; _n < 4; ++_n) {                                                   \
        acc[(M0_)][_n]     = __builtin_amdgcn_mfma_f32_16x16x32_bf16(afrag[_n][0], _b00, acc[(M0_)][_n], 0, 0, 0);     \
        acc[(M0_)][_n]     = __builtin_amdgcn_mfma_f32_16x16x32_bf16(afrag[_n][1], _b01, acc[(M0_)][_n], 0, 0, 0);     \
        acc[(M0_) + 1][_n] = __builtin_amdgcn_mfma_f32_16x16x32_bf16(afrag[_n][0], _b10, acc[(M0_) + 1][_n], 0, 0, 0); \
        acc[(M0_) + 1][_n] = __builtin_amdgcn_mfma_f32_16x16x32_bf16(afrag[_n][1], _b11, acc[(M0_) + 1][_n], 0, 0, 0); \
    }                                                                                  \
    __builtin_amdgcn_s_setprio(0);                                                     \
} while (0)

    STAGE(0, 0);   // prologue: K-tile 0 -> buf0

    for (int kk = 0; kk < 28; ++kk) {
        const unsigned cur = (kk & 1) ? 61440u : 0u;
        const unsigned nxt = cur ^ 61440u;
        const int kst = (kk < 27) ? kk + 1 : 27;

        STAGE(kst, nxt);
        if (doB4) { asm volatile("s_waitcnt vmcnt(8)" ::: "memory"); }
        else      { asm volatile("s_waitcnt vmcnt(7)" ::: "memory"); }
        __builtin_amdgcn_s_barrier();
        asm volatile("" ::: "memory");

        #pragma unroll
        for (int nn = 0; nn < 4; ++nn) {
            afrag[nn][0] = *(const bf16x8*)(lds + cur + aRow + nn * 2048 + fo0);
            afrag[nn][1] = *(const bf16x8*)(lds + cur + aRow + nn * 2048 + fo1);
        }
        BCHUNK(0, cur);
        BCHUNK(2, cur);
        BCHUNK(4, cur);
        {
            bf16x8 _b60 = *(const bf16x8*)(lds + cur + bRow + 6 * 2048 + fo0);
            bf16x8 _b61 = *(const bf16x8*)(lds + cur + bRow + 6 * 2048 + fo1);
            __builtin_amdgcn_s_setprio(1);
            #pragma unroll
            for (int _n = 0; _n < 4; ++_n) {
                acc[6][_n] = __builtin_amdgcn_mfma_f32_16x16x32_bf16(afrag[_n][0], _b60, acc[6][_n], 0, 0, 0);
                acc[6][_n] = __builtin_amdgcn_mfma_f32_16x16x32_bf16(afrag[_n][1], _b61, acc[6][_n], 0, 0, 0);
            }
            __builtin_amdgcn_s_setprio(0);
        }

        __builtin_amdgcn_s_barrier();
        asm volatile("" ::: "memory");
    }
#undef BCHUNK
#undef STAGE

    #pragma unroll
    for (int m = 0; m < 7; ++m) {
        int P = pix0 + wr * 112 + m * 16 + lr;
        int n = P / 3136, p = P % 3136;
        float* ob = out + (size_t)n * 802816 + p;
        #pragma unroll
        for (int nn = 0; nn < 4; ++nn) {
            int o = wc * 64 + nn * 16 + lg * 4;
            float* op = ob + (size_t)o * 3136;
            op[0 * 3136] = acc[m][nn][0];
            op[1 * 3136] = acc[m][nn][1];
            op[2 * 3136] = acc[m][nn][2];
            op[3 * 3136] = acc[m][nn][3];
        }
    }
}

// ---------------- kernel 3: out *= t1 (depthwise 5x5, LDS-tiled per (n,c) plane) --------
__global__ __launch_bounds__(256) void k_gate(const float* __restrict__ x,
                                              const float* __restrict__ w1,
                                              float* __restrict__ out) {
    const int b = blockIdx.x;
    const int c = b & 255, n = b >> 8;
    const int t = threadIdx.x;
    __shared__ float xs[60][60];

    float* lp = &xs[0][0];
    #pragma unroll
    for (int i = 0; i < 15; ++i) {
        int idx = t + i * 256;
        if (idx < 3600) lp[idx] = 0.f;
    }
    __syncthreads();

    const float* xc = x + (size_t)(n * 256 + c) * 3136;
    #pragma unroll
    for (int k = 0; k < 4; ++k) {
        int j = t + k * 256;
        if (j < 784) {
            f32x4 v = *(const f32x4*)(xc + j * 4);
            int p = j * 4;
            int h = p / 56, w = p % 56;
            xs[h + 2][w + 2 + 0] = v[0];
            xs[h + 2][w + 2 + 1] = v[1];
            xs[h + 2][w + 2 + 2] = v[2];
            xs[h + 2][w + 2 + 3] = v[3];
        }
    }

    const float* wk = w1 + c * 25;
    float wr[25];
    #pragma unroll
    for (int i = 0; i < 25; ++i) wr[i] = wk[i];
    __syncthreads();

    float* oc = out + (size_t)(n * 256 + c) * 3136;
    #pragma unroll
    for (int k = 0; k < 4; ++k) {
        int j = t + k * 256;
        if (j < 784) {
            int p = j * 4;
            int h = p / 56, w = p % 56;
            f32x4 o = *(f32x4*)(oc + p);
            f32x4 t1 = {0.f, 0.f, 0.f, 0.f};
            #pragma unroll
            for (int dy = 0; dy < 5; ++dy)
                #pragma unroll
                for (int dx = 0; dx < 5; ++dx) {
                    float wv = wr[dy * 5 + dx];
                    t1[0] = fmaf(wv, xs[h + dy][w + dx + 0], t1[0]);
                    t1[1] = fmaf(wv, xs[h + dy][w + dx + 1], t1[1]);
                    t1[2] = fmaf(wv, xs[h + dy][w + dx + 2], t1[2]);
                    t1[3] = fmaf(wv, xs[h + dy][w + dx + 3], t1[3]);
                }
            o *= t1;
            *(f32x4*)(oc + p) = o;
        }
    }
}

extern "C" void kernel_launch(void* const* d_in, const int* in_sizes, int n_in,
                              void* d_out, int out_size, void* d_ws, size_t ws_size,
                              hipStream_t stream) {
    const float* x  = (const float*)d_in[0];
    const float* w1 = (const float*)d_in[1];
    const float* w2 = (const float*)d_in[2];
    const float* w4 = (const float*)d_in[3];
    float* out = (float*)d_out;

    const size_t W4B_ELEMS = 256 * 1792;
    const size_t T2P_ELEMS = (size_t)16 * 74 * 56 * 256;
    if (ws_size < (W4B_ELEMS + T2P_ELEMS) * sizeof(unsigned short)) return;
    unsigned short* w4b = (unsigned short*)d_ws;
    unsigned short* t2p = w4b + W4B_ELEMS;

    k_w4conv<<<1792, 256, 0, stream>>>(w4, w4b);
    k_t2prep<<<16 * 74 * 8, 256, 0, stream>>>(x, w2, t2p);
    k_gemm8<<<224, 512, 122880, stream>>>(w4b, t2p, out);
    k_gate<<<4096, 256, 0, stream>>>(x, w1, out);
}